// Round 6
// baseline (163.391 us; speedup 1.0000x reference)
//
#include <hip/hip_runtime.h>

typedef unsigned short ushort_t;
typedef unsigned int uint_t;

typedef __bf16 bf16x8 __attribute__((ext_vector_type(8)));
typedef float f32x4 __attribute__((ext_vector_type(4)));

#define KK 588       // true K
#define KP 608       // padded K (19 * 32) -- B only
#define NN 1152      // N (output cols)
#define MM 32768     // M (output rows)
#define POSROWS 4096 // h*w per image
#define NSTEP 19     // KP/32
#define GRID 2304    // 8 xcd * 4 pp * 9 nt * 8 r
#define CHUNKS_PER_ROW 76               // KP/8
#define BCHUNKS (NN * CHUNKS_PER_ROW)   // 87552
#define BBLOCKS ((BCHUNKS + 255) / 256) // 342

#define AS1 __attribute__((address_space(1)))
#define AS3 __attribute__((address_space(3)))

// ---------------- helpers ----------------

__device__ __forceinline__ void cubic_taps(int dst, float* w, int* idx) {
    const float A = -0.75f;
    float src = (float)dst * 0.25f - 0.25f;   // (dst+0.5)*16/64 - 0.5
    int x0 = (int)floorf(src);
    #pragma unroll
    for (int k = -1; k <= 2; ++k) {
        int i = x0 + k;
        int ic = i < 0 ? 0 : (i > 15 ? 15 : i);
        float d = fabsf(src - (float)i);
        float wt;
        if (d <= 1.0f)      wt = ((A + 2.0f) * d - (A + 3.0f)) * d * d + 1.0f;
        else if (d < 2.0f)  wt = ((A * d - 5.0f * A) * d + 8.0f * A) * d - 4.0f * A;
        else                wt = 0.0f;
        w[k + 1] = wt;
        idx[k + 1] = ic;
    }
}

// ---------------- prep: cvt B (fp32->bf16, pad to KP) + pos table (+bias) ----------------

__global__ void prep_kernel(const float* __restrict__ wp, ushort_t* __restrict__ wb,
                            const float* __restrict__ pt, const float* __restrict__ bias,
                            float* __restrict__ pos) {
    int b = blockIdx.x;
    if (b < BBLOCKS) {
        // B conversion: (1152, 588) fp32 -> (1152, 608) bf16
        int c = b * 256 + threadIdx.x;
        if (c >= BCHUNKS) return;
        int row = c / CHUNKS_PER_ROW;
        int k0 = (c - row * CHUNKS_PER_ROW) * 8;
        const float* g = wp + (size_t)row * KK + k0;
        bf16x8 v;
        if (k0 + 8 <= KK) {
            f32x4 a = *(const f32x4*)g;
            f32x4 bb = *(const f32x4*)(g + 4);
            #pragma unroll
            for (int e = 0; e < 4; ++e) { v[e] = (__bf16)a[e]; v[e + 4] = (__bf16)bb[e]; }
        } else {
            #pragma unroll
            for (int e = 0; e < 8; ++e)
                v[e] = (k0 + e < KK) ? (__bf16)g[e] : (__bf16)0.f;
        }
        *(bf16x8*)(wb + (size_t)row * KP + k0) = v;
    } else {
        // pos row (rearranged) with bias folded in
        int n = b - BBLOCKS; // 0..4095
        int h = ((n >> 7) << 1) | ((n >> 1) & 1);
        int w = (((n >> 2) & 31) << 1) | (n & 1);
        float wh[4], ww[4];
        int ih[4], iw[4];
        cubic_taps(h, wh, ih);
        cubic_taps(w, ww, iw);
        const f32x4* pt4 = (const f32x4*)pt;
        const f32x4* bias4 = (const f32x4*)bias;
        for (int j = threadIdx.x; j < NN / 4; j += blockDim.x) {
            f32x4 s = bias4[j];
            #pragma unroll
            for (int a = 0; a < 4; ++a) {
                #pragma unroll
                for (int bq = 0; bq < 4; ++bq) {
                    float wt = wh[a] * ww[bq];
                    f32x4 vv = pt4[(ih[a] * 16 + iw[bq]) * (NN / 4) + j];
                    s.x += wt * vv.x; s.y += wt * vv.y; s.z += wt * vv.z; s.w += wt * vv.w;
                }
            }
            ((f32x4*)pos)[(size_t)n * (NN / 4) + j] = s;
        }
    }
}

// ---------------- fused GEMM: A staged as fp32 via global_load_lds ----------------
// A: [MM][KK] fp32 (DMA'd raw into LDS; cvt to bf16 at fragment read).
// B: [NN][KP] bf16 pre-converted (zero-padded k>=588, which annihilates A tail junk).
// out[m][n] = sum_k A[m][k]*B[n][k] + pos[m&4095][n]   (bias folded into pos)

__global__ __launch_bounds__(256)
void gemm_kernel(const float* __restrict__ A,
                 const ushort_t* __restrict__ Bbf,
                 const float* __restrict__ pos,
                 float* __restrict__ out) {
    __shared__ __align__(16) float    lA[2][128 * 32]; // fp32 tile, 16KB/buf, 8 slots/row swizzled
    __shared__ __align__(16) ushort_t lB[2][128 * 32]; // bf16 tile, 8KB/buf, 4 slots/row swizzled

    const int t = threadIdx.x;
    const int lane = t & 63;
    const int lm = lane & 15;
    const int lq = lane >> 4;
    const int wid = t >> 6;
    const int wm = wid >> 1, wn = wid & 1;

    // reuse-aware bijective swizzle: xcd = p&7; per p, a 72-block (nt,r) window.
    // 8 r's (same pos tile, same B panel) adjacent; 9 nt's (same A panel) within window.
    int blk = (int)blockIdx.x;
    int xcd = blk & 7;
    int local = blk >> 3;        // 0..287
    int pp = local / 72;         // 0..3
    int rem = local - pp * 72;   // 0..71
    int nt = rem >> 3;           // 0..8
    int r  = rem & 7;            // 0..7
    int p  = pp * 8 + xcd;       // 0..31 (pos panel id)
    int mt = r * 32 + p;         // 0..255
    const int bm = mt * 128;
    const int bn = nt * 128;

    f32x4 acc[4][4] = {};

    auto stageA = [&](int ks, int buf) { // 128 rows x 32 floats, 4 loads/thread
        const int k0 = ks * 32;
        #pragma unroll
        for (int j = 0; j < 4; ++j) {
            int idx = j * 256 + t;
            int row = idx >> 3;
            int slot = idx & 7;
            int sc = slot ^ (row & 7);            // source k-chunk for this dest slot
            int kf = k0 + sc * 4;
            // clamp OOB tail chunks (k>=588) to row start; junk * B-zero = 0
            const float* g = A + (size_t)(bm + row) * KK + ((kf <= KK - 4) ? kf : 0);
            float* lp = &lA[buf][(idx & ~63) * 4]; // wave-uniform base, 16B/lane
            __builtin_amdgcn_global_load_lds(
                (const AS1 void*)g, (AS3 void*)lp, 16, 0, 0);
        }
    };
    auto stageB = [&](int ks, int buf) { // 128 rows x 32 bf16, 2 loads/thread
        const int k0 = ks * 32;
        #pragma unroll
        for (int j = 0; j < 2; ++j) {
            int idx = j * 256 + t;
            int row = idx >> 2;
            int slot = idx & 3;
            int khi = slot ^ ((row >> 1) & 3);    // inverse swizzle on SOURCE
            const ushort_t* gB = Bbf + (size_t)(bn + row) * KP + k0 + khi * 8;
            ushort_t* lBp = &lB[buf][(size_t)(idx & ~63) * 8];
            __builtin_amdgcn_global_load_lds(
                (const AS1 void*)gB, (AS3 void*)lBp, 16, 0, 0);
        }
    };

    // prologue: tile 0 in flight (6 loads)
    stageA(0, 0); stageB(0, 0);

    for (int ks = 0; ks < NSTEP; ++ks) {
        const int cur = ks & 1;
        if (ks + 1 < NSTEP) {
            stageA(ks + 1, cur ^ 1);              // 6 more loads in flight
            stageB(ks + 1, cur ^ 1);
            asm volatile("s_waitcnt vmcnt(6)" ::: "memory"); // tile ks landed
        } else {
            asm volatile("s_waitcnt vmcnt(0)" ::: "memory");
        }
        __builtin_amdgcn_s_barrier();
        __builtin_amdgcn_sched_barrier(0);

        bf16x8 af[4], bfr[4];
        #pragma unroll
        for (int mi = 0; mi < 4; ++mi) {          // A: fp32 -> bf16 at read
            int row = wm * 64 + mi * 16 + lm;
            int s0 = (2 * lq) ^ (row & 7);
            const float* base = &lA[cur][row * 32];
            f32x4 v0 = *(const f32x4*)(base + s0 * 4);
            f32x4 v1 = *(const f32x4*)(base + (s0 ^ 1) * 4);
            #pragma unroll
            for (int e = 0; e < 4; ++e) {
                af[mi][e]     = (__bf16)v0[e];
                af[mi][e + 4] = (__bf16)v1[e];
            }
        }
        #pragma unroll
        for (int ni = 0; ni < 4; ++ni) {
            int row = wn * 64 + ni * 16 + lm;
            int slot = lq ^ ((row >> 1) & 3);
            bfr[ni] = *(const bf16x8*)(&lB[cur][row * 32 + slot * 8]);
        }
        #pragma unroll
        for (int mi = 0; mi < 4; ++mi)
            #pragma unroll
            for (int ni = 0; ni < 4; ++ni)
                acc[mi][ni] = __builtin_amdgcn_mfma_f32_16x16x32_bf16(
                    bfr[ni], af[mi], acc[mi][ni], 0, 0, 0); // swapped -> col-quad C layout

        asm volatile("s_waitcnt lgkmcnt(0)" ::: "memory");
        __builtin_amdgcn_sched_barrier(0);
        __builtin_amdgcn_s_barrier(); // buf cur free for restage next iter
    }

    // epilogue: swapped C-layout -> lane holds out[m][nb..nb+3]; bias folded in pos
    const int M0 = bm + wm * 64;
    const int N0 = bn + wn * 64;
    #pragma unroll
    for (int mi = 0; mi < 4; ++mi) {
        int m = M0 + mi * 16 + lm;
        const float* posrow = pos + (size_t)(m & (POSROWS - 1)) * NN;
        float* outrow = out + (size_t)m * NN;
        #pragma unroll
        for (int ni = 0; ni < 4; ++ni) {
            int nb = N0 + ni * 16 + lq * 4;
            f32x4 pv = *(const f32x4*)(posrow + nb);
            f32x4 v = acc[mi][ni];
            v.x += pv.x; v.y += pv.y; v.z += pv.z; v.w += pv.w;
            *(f32x4*)(outrow + nb) = v;
        }
    }
}

// ---------------- fallback (ws too small): naive fp32 ----------------

__global__ void fb_kernel(const float* __restrict__ A, const float* __restrict__ W,
                          const float* __restrict__ bias, const float* __restrict__ pt,
                          float* __restrict__ out) {
    __shared__ float sA[16][17], sB[16][17];
    int ty = threadIdx.y, tx = threadIdx.x;
    int row = blockIdx.y * 16 + ty; // M
    int col = blockIdx.x * 16 + tx; // N
    float acc = 0.f;
    for (int k0 = 0; k0 < KK; k0 += 16) {
        int ka = k0 + tx;
        sA[ty][tx] = (ka < KK) ? A[(size_t)row * KK + ka] : 0.f;
        sB[ty][tx] = (ka < KK) ? W[(size_t)(blockIdx.x * 16 + ty) * KK + ka] : 0.f;
        __syncthreads();
        #pragma unroll
        for (int kk = 0; kk < 16; ++kk)
            acc += sA[ty][kk] * sB[tx][kk];
        __syncthreads();
    }
    int n = row & (POSROWS - 1);
    int h = ((n >> 7) << 1) | ((n >> 1) & 1);
    int w = (((n >> 2) & 31) << 1) | (n & 1);
    float wh[4], ww[4]; int ih[4], iw[4];
    cubic_taps(h, wh, ih);
    cubic_taps(w, ww, iw);
    float pq = 0.f;
    #pragma unroll
    for (int a = 0; a < 4; ++a) {
        float rs = 0.f;
        #pragma unroll
        for (int b = 0; b < 4; ++b)
            rs += ww[b] * pt[(ih[a] * 16 + iw[b]) * NN + col];
        pq += wh[a] * rs;
    }
    out[(size_t)row * NN + col] = acc + bias[col] + pq;
}

// ---------------- launch ----------------

extern "C" void kernel_launch(void* const* d_in, const int* in_sizes, int n_in,
                              void* d_out, int out_size, void* d_ws, size_t ws_size,
                              hipStream_t stream) {
    const float* pv   = (const float*)d_in[0]; // (32768, 588)
    const float* wp   = (const float*)d_in[1]; // (1152, 588)
    const float* bias = (const float*)d_in[2]; // (1152,)
    const float* pt   = (const float*)d_in[3]; // (256, 1152)
    float* out = (float*)d_out;

    const size_t pos_bytes = (size_t)POSROWS * NN * 4;   // 18,874,368
    const size_t wb_bytes  = (size_t)NN * KP * 2;        //  1,400,832
    const size_t need = pos_bytes + wb_bytes;

    if (ws_size >= need) {
        float* pos = (float*)d_ws;
        ushort_t* wb = (ushort_t*)((char*)d_ws + pos_bytes);

        prep_kernel<<<BBLOCKS + POSROWS, 256, 0, stream>>>(wp, wb, pt, bias, pos);
        gemm_kernel<<<GRID, 256, 0, stream>>>(pv, wb, pos, out);
    } else {
        fb_kernel<<<dim3(NN / 16, MM / 16), dim3(16, 16), 0, stream>>>(pv, wp, bias, pt, out);
    }
}

// Round 7
// 123.829 us; speedup vs baseline: 1.3195x; 1.3195x over previous
//
#include <hip/hip_runtime.h>

typedef unsigned short ushort_t;
typedef unsigned int uint_t;

typedef __bf16 bf16x8 __attribute__((ext_vector_type(8)));
typedef float f32x4 __attribute__((ext_vector_type(4)));

#define KK 588       // true K
#define KP 608       // padded K (19 * 32)
#define NN 1152      // N (output cols)
#define MM 32768     // M (output rows)
#define POSROWS 4096 // h*w per image
#define NSTEP 19     // KP/32
#define GRID 2304    // 8 xcd * 4 pp * 9 nt * 8 r
#define CHUNKS_PER_ROW 76                    // KP/8
#define ACHUNKS (MM * CHUNKS_PER_ROW)        // 2,490,368
#define ABLOCKS (ACHUNKS / 256)              // 9728
#define BCHUNKS (NN * CHUNKS_PER_ROW)        // 87552
#define BBLOCKS ((BCHUNKS + 255) / 256)      // 342

#define AS1 __attribute__((address_space(1)))
#define AS3 __attribute__((address_space(3)))

// ---------------- helpers ----------------

__device__ __forceinline__ void cubic_taps(int dst, float* w, int* idx) {
    const float A = -0.75f;
    float src = (float)dst * 0.25f - 0.25f;   // (dst+0.5)*16/64 - 0.5
    int x0 = (int)floorf(src);
    #pragma unroll
    for (int k = -1; k <= 2; ++k) {
        int i = x0 + k;
        int ic = i < 0 ? 0 : (i > 15 ? 15 : i);
        float d = fabsf(src - (float)i);
        float wt;
        if (d <= 1.0f)      wt = ((A + 2.0f) * d - (A + 3.0f)) * d * d + 1.0f;
        else if (d < 2.0f)  wt = ((A * d - 5.0f * A) * d + 8.0f * A) * d - 4.0f * A;
        else                wt = 0.0f;
        w[k + 1] = wt;
        idx[k + 1] = ic;
    }
}

__device__ __forceinline__ void cvt_chunk(const float* __restrict__ src,
                                          ushort_t* __restrict__ dst, int c) {
    int row = c / CHUNKS_PER_ROW;
    int k0 = (c - row * CHUNKS_PER_ROW) * 8;
    const float* g = src + (size_t)row * KK + k0;
    bf16x8 v;
    if (k0 + 8 <= KK) {
        f32x4 a = *(const f32x4*)g;
        f32x4 b = *(const f32x4*)(g + 4);
        #pragma unroll
        for (int e = 0; e < 4; ++e) { v[e] = (__bf16)a[e]; v[e + 4] = (__bf16)b[e]; }
    } else {
        #pragma unroll
        for (int e = 0; e < 8; ++e)
            v[e] = (k0 + e < KK) ? (__bf16)g[e] : (__bf16)0.f;
    }
    *(bf16x8*)(dst + (size_t)row * KP + k0) = v;
}

// ---------------- prep: cvt A + cvt B (fp32->bf16, pad) + pos table (+bias) ----------------

__global__ void prep_kernel(const float* __restrict__ pv, ushort_t* __restrict__ pvb,
                            const float* __restrict__ wp, ushort_t* __restrict__ wb,
                            const float* __restrict__ pt, const float* __restrict__ bias,
                            float* __restrict__ pos) {
    int b = blockIdx.x;
    if (b < ABLOCKS) {
        cvt_chunk(pv, pvb, b * 256 + threadIdx.x);
    } else if (b < ABLOCKS + BBLOCKS) {
        int c = (b - ABLOCKS) * 256 + threadIdx.x;
        if (c < BCHUNKS) cvt_chunk(wp, wb, c);
    } else {
        // pos row (rearranged) with bias folded in
        int n = b - (ABLOCKS + BBLOCKS); // 0..4095
        int h = ((n >> 7) << 1) | ((n >> 1) & 1);
        int w = (((n >> 2) & 31) << 1) | (n & 1);
        float wh[4], ww[4];
        int ih[4], iw[4];
        cubic_taps(h, wh, ih);
        cubic_taps(w, ww, iw);
        const f32x4* pt4 = (const f32x4*)pt;
        const f32x4* bias4 = (const f32x4*)bias;
        for (int j = threadIdx.x; j < NN / 4; j += blockDim.x) {
            f32x4 s = bias4[j];
            #pragma unroll
            for (int a = 0; a < 4; ++a) {
                #pragma unroll
                for (int bq = 0; bq < 4; ++bq) {
                    float wt = wh[a] * ww[bq];
                    f32x4 vv = pt4[(ih[a] * 16 + iw[bq]) * (NN / 4) + j];
                    s.x += wt * vv.x; s.y += wt * vv.y; s.z += wt * vv.z; s.w += wt * vv.w;
                }
            }
            ((f32x4*)pos)[(size_t)n * (NN / 4) + j] = s;
        }
    }
}

// ---------------- bf16 MFMA GEMM + pos epilogue ----------------
// A: [MM][KP] bf16, B: [NN][KP] bf16. out[m][n] = sum_k A[m][k]*B[n][k] + pos[m&4095][n]
// R3 skeleton (3-buf global_load_lds, counted vmcnt) + reuse-aware XCD swizzle
// + swapped-operand MFMA -> float4 epilogue.

__global__ void gemm_kernel(const ushort_t* __restrict__ Abf,
                            const ushort_t* __restrict__ Bbf,
                            const float* __restrict__ pos,
                            float* __restrict__ out) {
    __shared__ __align__(16) ushort_t lA[3][128 * 32]; // [row][32k], 16B slots swizzled
    __shared__ __align__(16) ushort_t lB[3][128 * 32];

    const int t = threadIdx.x;
    const int lane = t & 63;
    const int lm = lane & 15;
    const int lq = lane >> 4;
    const int wid = t >> 6;
    const int wm = wid >> 1, wn = wid & 1;

    // reuse-aware bijective swizzle: per (xcd, pp) a 72-block window covering
    // 9 nt x 8 r. pos panel p = pp*8+xcd is read by exactly one window (19MB once);
    // A panel mt = r*32+p is read by exactly its 9-nt window (40MB once).
    int blk = (int)blockIdx.x;
    int xcd = blk & 7;
    int local = blk >> 3;        // 0..287
    int pp = local / 72;         // 0..3
    int rem = local - pp * 72;   // 0..71
    int nt = rem >> 3;           // 0..8
    int r  = rem & 7;            // 0..7
    int p  = pp * 8 + xcd;       // 0..31 (pos panel id)
    int mt = r * 32 + p;         // 0..255
    const int bm = mt * 128;
    const int bn = nt * 128;

    f32x4 acc[4][4] = {};

    auto stage = [&](int ks, int buf) {
        const int k0 = ks * 32;
        #pragma unroll
        for (int j = 0; j < 2; ++j) {
            int idx = j * 256 + t;
            int row = idx >> 2;
            int slot = idx & 3;
            int khi = slot ^ ((row >> 1) & 3); // inverse swizzle on SOURCE (lds dest linear)
            const ushort_t* gA = Abf + (size_t)(bm + row) * KP + k0 + khi * 8;
            const ushort_t* gB = Bbf + (size_t)(bn + row) * KP + k0 + khi * 8;
            ushort_t* lAp = &lA[buf][(size_t)(idx & ~63) * 8]; // wave-uniform base, 16B/lane
            ushort_t* lBp = &lB[buf][(size_t)(idx & ~63) * 8];
            __builtin_amdgcn_global_load_lds(
                (const AS1 void*)gA, (AS3 void*)lAp, 16, 0, 0);
            __builtin_amdgcn_global_load_lds(
                (const AS1 void*)gB, (AS3 void*)lBp, 16, 0, 0);
        }
    };

    // prologue: 2 tiles in flight
    stage(0, 0);
    stage(1, 1);

    for (int ks = 0; ks < NSTEP; ++ks) {
        const int cur = ks % 3;

        if (ks + 2 < NSTEP) {
            stage(ks + 2, (ks + 2) % 3);              // 4 more loads in flight
            asm volatile("s_waitcnt vmcnt(8)" ::: "memory"); // tile ks landed
        } else if (ks + 1 < NSTEP) {
            asm volatile("s_waitcnt vmcnt(4)" ::: "memory");
        } else {
            asm volatile("s_waitcnt vmcnt(0)" ::: "memory");
        }
        __builtin_amdgcn_s_barrier();
        __builtin_amdgcn_sched_barrier(0);

        bf16x8 af[4], bfr[4];
        #pragma unroll
        for (int mi = 0; mi < 4; ++mi) {
            int row = wm * 64 + mi * 16 + lm;
            int slot = lq ^ ((row >> 1) & 3);
            af[mi] = *(const bf16x8*)(&lA[cur][row * 32 + slot * 8]);
        }
        #pragma unroll
        for (int ni = 0; ni < 4; ++ni) {
            int row = wn * 64 + ni * 16 + lm;
            int slot = lq ^ ((row >> 1) & 3);
            bfr[ni] = *(const bf16x8*)(&lB[cur][row * 32 + slot * 8]);
        }
        #pragma unroll
        for (int mi = 0; mi < 4; ++mi)
            #pragma unroll
            for (int ni = 0; ni < 4; ++ni)
                acc[mi][ni] = __builtin_amdgcn_mfma_f32_16x16x32_bf16(
                    bfr[ni], af[mi], acc[mi][ni], 0, 0, 0); // swapped -> col-quad C layout

        asm volatile("s_waitcnt lgkmcnt(0)" ::: "memory");
        __builtin_amdgcn_s_barrier();
    }

    // epilogue: swapped C-layout -> lane holds out[m][nb..nb+3]; bias folded in pos
    const int M0 = bm + wm * 64;
    const int N0 = bn + wn * 64;
    #pragma unroll
    for (int mi = 0; mi < 4; ++mi) {
        int m = M0 + mi * 16 + lm;
        const float* posrow = pos + (size_t)(m & (POSROWS - 1)) * NN;
        float* outrow = out + (size_t)m * NN;
        #pragma unroll
        for (int ni = 0; ni < 4; ++ni) {
            int nb = N0 + ni * 16 + lq * 4;
            f32x4 pv4 = *(const f32x4*)(posrow + nb);
            f32x4 v = acc[mi][ni];
            v.x += pv4.x; v.y += pv4.y; v.z += pv4.z; v.w += pv4.w;
            *(f32x4*)(outrow + nb) = v;
        }
    }
}

// ---------------- fallback (ws too small): naive fp32 ----------------

__global__ void fb_kernel(const float* __restrict__ A, const float* __restrict__ W,
                          const float* __restrict__ bias, const float* __restrict__ pt,
                          float* __restrict__ out) {
    __shared__ float sA[16][17], sB[16][17];
    int ty = threadIdx.y, tx = threadIdx.x;
    int row = blockIdx.y * 16 + ty; // M
    int col = blockIdx.x * 16 + tx; // N
    float acc = 0.f;
    for (int k0 = 0; k0 < KK; k0 += 16) {
        int ka = k0 + tx;
        sA[ty][tx] = (ka < KK) ? A[(size_t)row * KK + ka] : 0.f;
        sB[ty][tx] = (ka < KK) ? W[(size_t)(blockIdx.x * 16 + ty) * KK + ka] : 0.f;
        __syncthreads();
        #pragma unroll
        for (int kk = 0; kk < 16; ++kk)
            acc += sA[ty][kk] * sB[tx][kk];
        __syncthreads();
    }
    int n = row & (POSROWS - 1);
    int h = ((n >> 7) << 1) | ((n >> 1) & 1);
    int w = (((n >> 2) & 31) << 1) | (n & 1);
    float wh[4], ww[4]; int ih[4], iw[4];
    cubic_taps(h, wh, ih);
    cubic_taps(w, ww, iw);
    float pq = 0.f;
    #pragma unroll
    for (int a = 0; a < 4; ++a) {
        float rs = 0.f;
        #pragma unroll
        for (int b = 0; b < 4; ++b)
            rs += ww[b] * pt[(ih[a] * 16 + iw[b]) * NN + col];
        pq += wh[a] * rs;
    }
    out[(size_t)row * NN + col] = acc + bias[col] + pq;
}

// ---------------- launch ----------------

extern "C" void kernel_launch(void* const* d_in, const int* in_sizes, int n_in,
                              void* d_out, int out_size, void* d_ws, size_t ws_size,
                              hipStream_t stream) {
    const float* pv   = (const float*)d_in[0]; // (32768, 588)
    const float* wp   = (const float*)d_in[1]; // (1152, 588)
    const float* bias = (const float*)d_in[2]; // (1152,)
    const float* pt   = (const float*)d_in[3]; // (256, 1152)
    float* out = (float*)d_out;

    const size_t pos_bytes = (size_t)POSROWS * NN * 4;   // 18,874,368
    const size_t pvb_bytes = (size_t)MM * KP * 2;        // 39,845,888
    const size_t wb_bytes  = (size_t)NN * KP * 2;        //  1,400,832
    const size_t need = pos_bytes + pvb_bytes + wb_bytes;

    if (ws_size >= need) {
        float* pos = (float*)d_ws;
        ushort_t* pvb = (ushort_t*)((char*)d_ws + pos_bytes);
        ushort_t* wb  = (ushort_t*)((char*)d_ws + pos_bytes + pvb_bytes);

        prep_kernel<<<ABLOCKS + BBLOCKS + POSROWS, 256, 0, stream>>>(
            pv, pvb, wp, wb, pt, bias, pos);
        gemm_kernel<<<GRID, 256, 0, stream>>>(pvb, wb, pos, out);
    } else {
        fb_kernel<<<dim3(NN / 16, MM / 16), dim3(16, 16), 0, stream>>>(pv, wp, bias, pt, out);
    }
}